// Round 3
// baseline (337.091 us; speedup 1.0000x reference)
//
#include <hip/hip_runtime.h>

typedef _Float16 half2_t __attribute__((ext_vector_type(2)));
typedef unsigned int uint_t;

#define B_  64
#define T_  256
#define F_  16
#define H_  128

__device__ __forceinline__ float rcp_(float x)  { return __builtin_amdgcn_rcpf(x); }
__device__ __forceinline__ float sigm(float x)  { return rcp_(1.0f + __expf(-x)); }
__device__ __forceinline__ float tanh_(float x) { return 2.0f * rcp_(1.0f + __expf(-2.0f * x)) - 1.0f; }

#if __has_builtin(__builtin_amdgcn_fdot2)
__device__ __forceinline__ float dot2(uint_t w, uint_t h, float a) {
    return __builtin_amdgcn_fdot2(__builtin_bit_cast(half2_t, w),
                                  __builtin_bit_cast(half2_t, h), a, false);
}
#else
__device__ __forceinline__ float dot2(uint_t w, uint_t h, float a) {
    half2_t W = __builtin_bit_cast(half2_t, w), H = __builtin_bit_cast(half2_t, h);
    return a + (float)W[0] * (float)H[0] + (float)W[1] * (float)H[1];
}
#endif

// Kernel 1: repack W_hh [F,4H,H] fp32 -> f16-pair layout keyed to the main kernel's
// per-thread register file. Thread tid=(i,ks) of block f owns rows {i+128m} x k-slice
// [32ks,32ks+32). Packed as uint4 wt[(f*16+q)*512+tid], component e: dword dd=q*4+e,
// m=dd>>4, kk=dd&15 -> f16 pair W[f, i+128m, 32ks+2kk .. +1].
__global__ void repack_w(const float* __restrict__ whh, uint_t* __restrict__ wt) {
    const int f = blockIdx.x, tid = threadIdx.x;
    const int i = tid >> 2, ks = tid & 3;
    const float* base = whh + (size_t)f * 512 * 128;
#pragma unroll
    for (int q = 0; q < 16; ++q) {
        uint_t tmp[4];
#pragma unroll
        for (int e = 0; e < 4; ++e) {
            int dd = q * 4 + e, m = dd >> 4, kk = dd & 15;
            int row = i + 128 * m, k0 = 32 * ks + 2 * kk;
            half2_t h = { (_Float16)base[row * 128 + k0], (_Float16)base[row * 128 + k0 + 1] };
            tmp[e] = __builtin_bit_cast(uint_t, h);
        }
        uint4 out = { tmp[0], tmp[1], tmp[2], tmp[3] };
        ((uint4*)wt)[((size_t)f * 16 + q) * 512 + tid] = out;
    }
}

// Kernel 2: one block per (f,b), 512 threads. Thread (i,ks): 4 gate rows x 32-k slice,
// weights held in 16 uint4 VGPRs. The per-iteration empty asm redefines the weight
// values (opaque), making them loop-carried -> the compiler CANNOT re-load them from
// memory inside the loop (R2 failure mode: VGPR=48, weights re-streamed from L2 at
// 34 TB/s = the whole runtime).
__global__ __launch_bounds__(512, 4) void lstm_main(
    const float* __restrict__ x, const int* __restrict__ index,
    const float* __restrict__ wih_g, const float* __restrict__ bias_g,
    const uint_t* __restrict__ wt, float* __restrict__ hout)
{
    __shared__ float xsh[T_];
    __shared__ alignas(16) unsigned short hsh[2][H_];

    const int f = blockIdx.x, b = blockIdx.y;
    const int tid = threadIdx.x;
    const int i = tid >> 2, ks = tid & 3;

    // weight preload: 16 coalesced uint4 loads
    uint4 w[16];
    const uint4* src = (const uint4*)wt + (size_t)f * 16 * 512 + tid;
#pragma unroll
    for (int q = 0; q < 16; ++q) w[q] = src[q * 512];

    float wih4[4], b4q[4];
#pragma unroll
    for (int m = 0; m < 4; ++m) {
        wih4[m] = wih_g[f * 512 + 128 * m + i];
        b4q[m]  = bias_g[f * 512 + 128 * m + i] * 0.25f;  // summed 4x by the shfl reduce
    }

    if (tid < T_) xsh[tid] = x[((size_t)b * T_ + tid) * F_ + f];
    if (tid < H_) hsh[0][tid] = 0;

    const int start = index[2 * b], end = index[2 * b + 1];
    float c = 0.0f, hval = 0.0f;
    int p = 0;

    for (int t = start; t < end; ++t) {
        // Pin weights in VGPRs: redefine them each iteration so re-loading is illegal.
#pragma unroll
        for (int q = 0; q < 16; ++q)
            asm volatile("" : "+v"(w[q].x), "+v"(w[q].y), "+v"(w[q].z), "+v"(w[q].w));

        __syncthreads();                       // hsh[p] (and xsh on first iter) visible
        const uint4* h4 = (const uint4*)(&hsh[p][ks * 32]);
        float acc[4] = { b4q[0], b4q[1], b4q[2], b4q[3] };
#pragma unroll
        for (int q = 0; q < 4; ++q) {
            uint4 hq = h4[q];
#pragma unroll
            for (int m = 0; m < 4; ++m) {
                uint4 wq = w[m * 4 + q];
                acc[m] = dot2(wq.x, hq.x, acc[m]);
                acc[m] = dot2(wq.y, hq.y, acc[m]);
                acc[m] = dot2(wq.z, hq.z, acc[m]);
                acc[m] = dot2(wq.w, hq.w, acc[m]);
            }
        }
        // combine the 4 k-slices (lanes 4i'+ks, in-wave)
#pragma unroll
        for (int m = 0; m < 4; ++m) {
            acc[m] += __shfl_xor(acc[m], 1, 64);
            acc[m] += __shfl_xor(acc[m], 2, 64);
        }
        float xt = xsh[t];
        float pi = fmaf(xt, wih4[0], acc[0]);
        float pf = fmaf(xt, wih4[1], acc[1]);
        float pg = fmaf(xt, wih4[2], acc[2]);
        float po = fmaf(xt, wih4[3], acc[3]);
        float gi = sigm(pi), gf = sigm(pf), gg = tanh_(pg), go = sigm(po);
        c = fmaf(gf, c, gi * gg);
        hval = go * tanh_(c);
        if (ks == 0) {
            _Float16 hf = (_Float16)hval;
            hsh[p ^ 1][i] = __builtin_bit_cast(unsigned short, hf);
        }
        p ^= 1;
    }
    if (ks == 0) hout[((size_t)b * F_ + f) * H_ + i] = hval;
}

// Kernel 3: per-batch epilogue: mean over H -> conv3 (pad 1) -> sigmoid gate -> gated fc.
__global__ void epilogue(const float* __restrict__ hout, const float* __restrict__ conv_w,
                         const float* __restrict__ fc_w, const float* __restrict__ fc_b,
                         float* __restrict__ out)
{
    const int b = blockIdx.x, t = threadIdx.x;   // 128 threads
    const int lane = t & 63, wv = t >> 6;
    __shared__ float part[2][16];
    __shared__ float gate_sh[16];

    float hv[16];
#pragma unroll
    for (int f = 0; f < 16; ++f) hv[f] = hout[((size_t)b * 16 + f) * 128 + t];

#pragma unroll
    for (int f = 0; f < 16; ++f) {
        float s = hv[f];
#pragma unroll
        for (int off = 32; off >= 1; off >>= 1) s += __shfl_down(s, off, 64);
        if (lane == 0) part[wv][f] = s;
    }
    __syncthreads();
    if (t < 16) gate_sh[t] = (part[0][t] + part[1][t]) * (1.0f / 128.0f);  // means
    __syncthreads();
    float gate = 0.0f;
    if (t < 16) {
        float l  = (t > 0)  ? gate_sh[t - 1] : 0.0f;
        float mi = gate_sh[t];
        float r  = (t < 15) ? gate_sh[t + 1] : 0.0f;
        gate = sigm(fmaf(l, conv_w[0], fmaf(mi, conv_w[1], r * conv_w[2])));
    }
    __syncthreads();
    if (t < 16) gate_sh[t] = gate;
    __syncthreads();

    float acc0 = 0.0f, acc1 = 0.0f;
    const float2* fw2 = (const float2*)fc_w;
#pragma unroll
    for (int f = 0; f < 16; ++f) {
        float hg = hv[f] * gate_sh[f];
        float2 w2 = fw2[f * 128 + t];
        acc0 = fmaf(hg, w2.x, acc0);
        acc1 = fmaf(hg, w2.y, acc1);
    }
#pragma unroll
    for (int off = 32; off >= 1; off >>= 1) {
        acc0 += __shfl_down(acc0, off, 64);
        acc1 += __shfl_down(acc1, off, 64);
    }
    if (lane == 0) { part[wv][0] = acc0; part[wv][1] = acc1; }
    __syncthreads();
    if (t == 0) {
        out[b * 2 + 0] = part[0][0] + part[1][0] + fc_b[0];
        out[b * 2 + 1] = part[0][1] + part[1][1] + fc_b[1];
    }
}

extern "C" void kernel_launch(void* const* d_in, const int* in_sizes, int n_in,
                              void* d_out, int out_size, void* d_ws, size_t ws_size,
                              hipStream_t stream) {
    const float* x      = (const float*)d_in[0];
    const int*   index  = (const int*)  d_in[1];
    const float* W_ih   = (const float*)d_in[2];
    const float* W_hh   = (const float*)d_in[3];
    const float* bias   = (const float*)d_in[4];
    const float* conv_w = (const float*)d_in[5];
    const float* fc_w   = (const float*)d_in[6];
    const float* fc_b   = (const float*)d_in[7];
    float* out = (float*)d_out;

    uint_t* wt   = (uint_t*)d_ws;                          // 16*16*512 uint4 = 2 MB
    float*  hout = (float*)((char*)d_ws + 2 * 1024 * 1024); // 64*16*128 fp32 = 512 KB

    repack_w<<<F_, 512, 0, stream>>>(W_hh, wt);
    lstm_main<<<dim3(F_, B_), 512, 0, stream>>>(x, index, W_ih, bias, wt, hout);
    epilogue<<<B_, 128, 0, stream>>>(hout, conv_w, fc_w, fc_b, out);
}

// Round 4
// 267.753 us; speedup vs baseline: 1.2590x; 1.2590x over previous
//
#include <hip/hip_runtime.h>

typedef _Float16 half2_t __attribute__((ext_vector_type(2)));
typedef unsigned int uint_t;
typedef uint_t uint4v __attribute__((ext_vector_type(4)));

#define B_  64
#define T_  256
#define F_  16
#define H_  128

__device__ __forceinline__ float rcp_(float x)  { return __builtin_amdgcn_rcpf(x); }
__device__ __forceinline__ float sigm(float x)  { return rcp_(1.0f + __expf(-x)); }
__device__ __forceinline__ float tanh_(float x) { return 2.0f * rcp_(1.0f + __expf(-2.0f * x)) - 1.0f; }

#if __has_builtin(__builtin_amdgcn_fdot2)
__device__ __forceinline__ float dot2(uint_t w, uint_t h, float a) {
    return __builtin_amdgcn_fdot2(__builtin_bit_cast(half2_t, w),
                                  __builtin_bit_cast(half2_t, h), a, false);
}
#else
__device__ __forceinline__ float dot2(uint_t w, uint_t h, float a) {
    half2_t W = __builtin_bit_cast(half2_t, w), H = __builtin_bit_cast(half2_t, h);
    return a + (float)W[0] * (float)H[0] + (float)W[1] * (float)H[1];
}
#endif

// In-quad butterfly add via DPP (lanes 4q..4q+3 share i; ks = lane&3).
// ctrl 0xB1 = quad_perm[1,0,3,2] (xor 1), 0x4E = quad_perm[2,3,0,1] (xor 2).
template <int CTRL>
__device__ __forceinline__ float qadd(float v) {
    int t = __builtin_amdgcn_update_dpp(0, __builtin_bit_cast(int, v), CTRL, 0xF, 0xF, true);
    return v + __builtin_bit_cast(float, t);
}

// Kernel 1: repack W_hh [F,4H,H] fp32 -> f16-pair layout keyed to the main kernel's
// per-thread register file. Thread tid=(i,ks) of block f owns rows {i+128m} x k-slice
// [32ks,32ks+32). Packed as uint4 wt[(f*16+q)*512+tid], component e: dword dd=q*4+e,
// m=dd>>4, kk=dd&15 -> f16 pair W[f, i+128m, 32ks+2kk .. +1].
__global__ void repack_w(const float* __restrict__ whh, uint_t* __restrict__ wt) {
    const int f = blockIdx.x, tid = threadIdx.x;
    const int i = tid >> 2, ks = tid & 3;
    const float* base = whh + (size_t)f * 512 * 128;
#pragma unroll
    for (int q = 0; q < 16; ++q) {
        uint_t tmp[4];
#pragma unroll
        for (int e = 0; e < 4; ++e) {
            int dd = q * 4 + e, m = dd >> 4, kk = dd & 15;
            int row = i + 128 * m, k0 = 32 * ks + 2 * kk;
            half2_t h = { (_Float16)base[row * 128 + k0], (_Float16)base[row * 128 + k0 + 1] };
            tmp[e] = __builtin_bit_cast(uint_t, h);
        }
        uint4 out = { tmp[0], tmp[1], tmp[2], tmp[3] };
        ((uint4*)wt)[((size_t)f * 16 + q) * 512 + tid] = out;
    }
}

// Kernel 2: one block per (f,b), 512 threads. Thread (i,ks): 4 gate rows x 32-k slice.
// Weights are loaded via inline-asm global_load_dwordx4 -> the values are opaque asm
// outputs the compiler CANNOT rematerialize by re-loading (R2/R3 failure mode: loads
// sunk into the loop, 11 GB of L2 weight re-streaming = the entire 335 us runtime).
// k-slice reduction via DPP quad_perm (VALU) instead of __shfl_xor (DS pipe).
__global__ __launch_bounds__(512, 4) void lstm_main(
    const float* __restrict__ x, const int* __restrict__ index,
    const float* __restrict__ wih_g, const float* __restrict__ bias_g,
    const uint_t* __restrict__ wt, float* __restrict__ hout)
{
    __shared__ float xsh[T_];
    __shared__ alignas(16) unsigned short hsh[2][H_];

    const int f = blockIdx.x, b = blockIdx.y;
    const int tid = threadIdx.x;
    const int i = tid >> 2;

    // ---- opaque weight preload: 16 x global_load_dwordx4 into VGPRs ----
    uint4v w[16];
    {
        const char* src = (const char*)wt + (((size_t)f * 16) * 512 + tid) * 16;
#pragma unroll
        for (int q = 0; q < 16; ++q) {
            unsigned long long addr = (unsigned long long)(src + (size_t)q * 512 * 16);
            asm volatile("global_load_dwordx4 %0, %1, off" : "=v"(w[q]) : "v"(addr));
        }
        asm volatile("s_waitcnt vmcnt(0)");
        __builtin_amdgcn_sched_barrier(0);
    }

    float wih4[4], b4[4];
#pragma unroll
    for (int m = 0; m < 4; ++m) {
        wih4[m] = wih_g[f * 512 + 128 * m + i];
        b4[m]   = bias_g[f * 512 + 128 * m + i] * 0.25f;  // summed 4x by the quad reduce
    }

    if (tid < T_) xsh[tid] = x[((size_t)b * T_ + tid) * F_ + f];
    if (tid < H_) hsh[0][tid] = 0;

    const int start = index[2 * b], end = index[2 * b + 1];
    float c = 0.0f, hval = 0.0f;
    int p = 0;

    for (int t = start; t < end; ++t) {
        __syncthreads();                       // hsh[p] (and xsh on first iter) visible
        const uint4v* h4 = (const uint4v*)(&hsh[p][(tid & 3) * 32]);
        float acc[4] = { b4[0], b4[1], b4[2], b4[3] };
#pragma unroll
        for (int q = 0; q < 4; ++q) {
            uint4v hq = h4[q];
#pragma unroll
            for (int m = 0; m < 4; ++m) {
                uint4v wq = w[m * 4 + q];
                acc[m] = dot2(wq.x, hq.x, acc[m]);
                acc[m] = dot2(wq.y, hq.y, acc[m]);
                acc[m] = dot2(wq.z, hq.z, acc[m]);
                acc[m] = dot2(wq.w, hq.w, acc[m]);
            }
        }
        // combine the 4 k-slices: in-quad DPP butterfly (no DS traffic)
#pragma unroll
        for (int m = 0; m < 4; ++m) {
            acc[m] = qadd<0xB1>(acc[m]);
            acc[m] = qadd<0x4E>(acc[m]);
        }
        float xt = xsh[t];
        float pi = fmaf(xt, wih4[0], acc[0]);
        float pf = fmaf(xt, wih4[1], acc[1]);
        float pg = fmaf(xt, wih4[2], acc[2]);
        float po = fmaf(xt, wih4[3], acc[3]);
        float gi = sigm(pi), gf = sigm(pf), gg = tanh_(pg), go = sigm(po);
        c = fmaf(gf, c, gi * gg);
        hval = go * tanh_(c);
        if ((tid & 3) == 0) {
            _Float16 hf = (_Float16)hval;
            hsh[p ^ 1][i] = __builtin_bit_cast(unsigned short, hf);
        }
        p ^= 1;
    }
    if ((tid & 3) == 0) hout[((size_t)b * F_ + f) * H_ + i] = hval;
}

// Kernel 3: per-batch epilogue: mean over H -> conv3 (pad 1) -> sigmoid gate -> gated fc.
__global__ void epilogue(const float* __restrict__ hout, const float* __restrict__ conv_w,
                         const float* __restrict__ fc_w, const float* __restrict__ fc_b,
                         float* __restrict__ out)
{
    const int b = blockIdx.x, t = threadIdx.x;   // 128 threads
    const int lane = t & 63, wv = t >> 6;
    __shared__ float part[2][16];
    __shared__ float gate_sh[16];

    float hv[16];
#pragma unroll
    for (int f = 0; f < 16; ++f) hv[f] = hout[((size_t)b * 16 + f) * 128 + t];

#pragma unroll
    for (int f = 0; f < 16; ++f) {
        float s = hv[f];
#pragma unroll
        for (int off = 32; off >= 1; off >>= 1) s += __shfl_down(s, off, 64);
        if (lane == 0) part[wv][f] = s;
    }
    __syncthreads();
    if (t < 16) gate_sh[t] = (part[0][t] + part[1][t]) * (1.0f / 128.0f);  // means
    __syncthreads();
    float gate = 0.0f;
    if (t < 16) {
        float l  = (t > 0)  ? gate_sh[t - 1] : 0.0f;
        float mi = gate_sh[t];
        float r  = (t < 15) ? gate_sh[t + 1] : 0.0f;
        gate = sigm(fmaf(l, conv_w[0], fmaf(mi, conv_w[1], r * conv_w[2])));
    }
    __syncthreads();
    if (t < 16) gate_sh[t] = gate;
    __syncthreads();

    float acc0 = 0.0f, acc1 = 0.0f;
    const float2* fw2 = (const float2*)fc_w;
#pragma unroll
    for (int f = 0; f < 16; ++f) {
        float hg = hv[f] * gate_sh[f];
        float2 w2 = fw2[f * 128 + t];
        acc0 = fmaf(hg, w2.x, acc0);
        acc1 = fmaf(hg, w2.y, acc1);
    }
#pragma unroll
    for (int off = 32; off >= 1; off >>= 1) {
        acc0 += __shfl_down(acc0, off, 64);
        acc1 += __shfl_down(acc1, off, 64);
    }
    if (lane == 0) { part[wv][0] = acc0; part[wv][1] = acc1; }
    __syncthreads();
    if (t == 0) {
        out[b * 2 + 0] = part[0][0] + part[1][0] + fc_b[0];
        out[b * 2 + 1] = part[0][1] + part[1][1] + fc_b[1];
    }
}

extern "C" void kernel_launch(void* const* d_in, const int* in_sizes, int n_in,
                              void* d_out, int out_size, void* d_ws, size_t ws_size,
                              hipStream_t stream) {
    const float* x      = (const float*)d_in[0];
    const int*   index  = (const int*)  d_in[1];
    const float* W_ih   = (const float*)d_in[2];
    const float* W_hh   = (const float*)d_in[3];
    const float* bias   = (const float*)d_in[4];
    const float* conv_w = (const float*)d_in[5];
    const float* fc_w   = (const float*)d_in[6];
    const float* fc_b   = (const float*)d_in[7];
    float* out = (float*)d_out;

    uint_t* wt   = (uint_t*)d_ws;                          // 16*16*512 uint4 = 2 MB
    float*  hout = (float*)((char*)d_ws + 2 * 1024 * 1024); // 64*16*128 fp32 = 512 KB

    repack_w<<<F_, 512, 0, stream>>>(W_hh, wt);
    lstm_main<<<dim3(F_, B_), 512, 0, stream>>>(x, index, W_ih, bias, wt, hout);
    epilogue<<<B_, 128, 0, stream>>>(hout, conv_w, fc_w, fc_b, out);
}